// Round 4
// baseline (2642.771 us; speedup 1.0000x reference)
//
#include <hip/hip_runtime.h>
#include <math.h>

// Problem constants
#define H_     8
#define D_     64
#define TOPK_  32
#define NUMB_  1000
#define DIM_   1024
#define BATCH_ 4
#define SEQ_   2048
#define INNER_ 512                  // H*D
#define TOK_   (BATCH_*SEQ_)        // 8192
#define ROWS_  (BATCH_*H_*SEQ_)     // 65536

// Phase split: 2 phases, each covers 2 batches = 4096 tokens = 32768 sim rows.
#define PH_TOK_  4096
#define PH_ROWS_ 32768

// ---------------------------------------------------------------------------
// Workspace layout — TOTAL 49 MiB.
//   [0)          diagD   fp32 1000*64            = 256,000 B
//   [256000)     kT      fp32 64*1000            = 256,000 B
//   [512000)     psiRow  int  1000               =   4,000 B
//   [1 MiB)      V       fp32 8192*512           = 16 MiB   (all tokens)
//   [17 MiB)     OutMid  fp32 8192*512           = 16 MiB   (all tokens)
//   [33 MiB)     Qh      fp64 4096*512           = 16 MiB   (per-phase half)
// ---------------------------------------------------------------------------

// ---------------------------------------------------------------------------
// K0: diag(b_mat) -> diagD[n][d]; transpose k_vec -> kT[d][n]; psiRow = -1.
// ---------------------------------------------------------------------------
__global__ void k0_prep(const float* __restrict__ b_mat,
                        const float* __restrict__ k_vec,
                        float* __restrict__ diagD,
                        float* __restrict__ kT,
                        int*   __restrict__ psiRow) {
    int t = blockIdx.x * 256 + threadIdx.x;
    if (t < NUMB_ * D_) {
        int n = t >> 6, d = t & 63;
        diagD[t] = b_mat[n * (D_ * D_) + d * (D_ + 1)];   // b_mat[n][d][d]
        kT[d * NUMB_ + n] = k_vec[t];                     // k_vec[n][d]
    }
    if (t < NUMB_) psiRow[t] = -1;
}

// ---------------------------------------------------------------------------
// K1: qv = x @ W_qv for tokens [tokBase, tokBase+PH_TOK_), fp64 accumulation
//     of exact fp32 products (order-independent => stable top-k later).
//     cols [0,512)    -> Qh (fp64, phase-local rows)
//     cols [512,1024) -> V  (fp32, global rows)
// ---------------------------------------------------------------------------
#define BK1 16
__global__ __launch_bounds__(256) void k1_qv(const float* __restrict__ x,
                                             const float* __restrict__ Wqv,
                                             double* __restrict__ Qh,
                                             float*  __restrict__ V,
                                             int tokBase) {
    __shared__ float xs[64][BK1 + 1];
    __shared__ float ws[BK1][64 + 1];
    const int tx = threadIdx.x & 15, ty = threadIdx.x >> 4;
    const int mBase = tokBase + blockIdx.y * 64;   // global token row
    const int nBase = blockIdx.x * 64;

    double acc[4][4];
#pragma unroll
    for (int a = 0; a < 4; a++)
#pragma unroll
        for (int b = 0; b < 4; b++) acc[a][b] = 0.0;

    for (int k0 = 0; k0 < DIM_; k0 += BK1) {
        for (int i = threadIdx.x; i < 64 * BK1; i += 256) {
            int r = i >> 4, kk = i & 15;
            xs[r][kk] = x[(size_t)(mBase + r) * DIM_ + k0 + kk];
        }
        for (int i = threadIdx.x; i < BK1 * 64; i += 256) {
            int kk = i >> 6, c = i & 63;
            ws[kk][c] = Wqv[(size_t)(k0 + kk) * (2 * INNER_) + nBase + c];
        }
        __syncthreads();
#pragma unroll
        for (int kk = 0; kk < BK1; ++kk) {
            float xa[4], wb[4];
#pragma unroll
            for (int a = 0; a < 4; a++) xa[a] = xs[ty * 4 + a][kk];
#pragma unroll
            for (int b = 0; b < 4; b++) wb[b] = ws[kk][tx * 4 + b];
#pragma unroll
            for (int a = 0; a < 4; a++)
#pragma unroll
                for (int b = 0; b < 4; b++)
                    acc[a][b] += (double)xa[a] * (double)wb[b];
        }
        __syncthreads();
    }

    const int mr = mBase + ty * 4, nc = nBase + tx * 4;
    if (nc < INNER_) {
#pragma unroll
        for (int a = 0; a < 4; a++)
#pragma unroll
            for (int b = 0; b < 4; b++)
                Qh[(size_t)(mr - tokBase + a) * INNER_ + nc + b] = acc[a][b];
    } else {
#pragma unroll
        for (int a = 0; a < 4; a++)
#pragma unroll
            for (int b = 0; b < 4; b++)
                V[(size_t)(mr + a) * INNER_ + (nc - INNER_) + b] = (float)acc[a][b];
    }
}

// ---------------------------------------------------------------------------
// K2: rows s in [sBase0, sBase0 + PH_ROWS_); one wave handles 4 rows.
//     sim[n] = sum_d q[d]*k_vec[n][d]  (fp64, exact products)
//     top-32 (desc value, lowest index on tie) -> softmax (scale 0.125 exact)
//     spike = (diag*v > 0); out_d = sum_k attn_k*spike*o_vec[n_k][d]
//     psi winner: atomicMax(psiRow[n], s) == numpy last-write-wins (C order)
// ---------------------------------------------------------------------------
__global__ __launch_bounds__(256) void k2_sim(const double* __restrict__ Qh,
                                              const float*  __restrict__ V,
                                              const float*  __restrict__ kT,
                                              const float*  __restrict__ diagD,
                                              const float*  __restrict__ o_vec,
                                              float* __restrict__ OutMid,
                                              int*   __restrict__ psiRow,
                                              int sBase0, int tokOff) {
    __shared__ double qld[4][4][64];          // [wave][row][d]
    const int lane = threadIdx.x & 63;
    const int wid  = threadIdx.x >> 6;
    const int g    = blockIdx.x * 4 + wid;
    const int sBase = sBase0 + g * 4;

#pragma unroll
    for (int r = 0; r < 4; r++) {
        int s = sBase + r;
        int b = s >> 14, h = (s >> 11) & 7, i = s & 2047;
        int tok = b * SEQ_ + i;
        qld[wid][r][lane] = Qh[(size_t)(tok - tokOff) * INNER_ + h * D_ + lane];
    }
    __syncthreads();

    double acc[4][16];
#pragma unroll
    for (int r = 0; r < 4; r++)
#pragma unroll
        for (int nb = 0; nb < 16; nb++) acc[r][nb] = 0.0;

    for (int d = 0; d < 64; ++d) {
        double q0 = qld[wid][0][d];
        double q1 = qld[wid][1][d];
        double q2 = qld[wid][2][d];
        double q3 = qld[wid][3][d];
        const float* kp = kT + d * NUMB_;
#pragma unroll
        for (int nb = 0; nb < 16; ++nb) {
            int n = nb * 64 + lane;
            float kv = (n < NUMB_) ? kp[n] : 0.f;
            double kd = (double)kv;
            acc[0][nb] += q0 * kd;
            acc[1][nb] += q1 * kd;
            acc[2][nb] += q2 * kd;
            acc[3][nb] += q3 * kd;
        }
    }

#pragma unroll
    for (int r = 0; r < 4; r++) {
        int s = sBase + r;
        int b = s >> 14, h = (s >> 11) & 7, i = s & 2047;
        int tok = b * SEQ_ + i;
        float vlane = V[(size_t)tok * INNER_ + h * D_ + lane];

        unsigned mask = 0;
        double t0 = 0.0;
        float esum = 0.f, outAcc = 0.f;

        for (int k = 0; k < TOPK_; k++) {
            // lane-local argmax over unmasked brains (ascending n scan with
            // strict > keeps the lowest index on exact ties)
            double bv = -1e300; int bn = 0x7fffffff;
#pragma unroll
            for (int nb = 0; nb < 16; ++nb) {
                int n = nb * 64 + lane;
                if (n < NUMB_ && !(mask & (1u << nb))) {
                    double v = acc[r][nb];
                    if (v > bv) { bv = v; bn = n; }
                }
            }
            // wave butterfly argmax; tie -> smaller index (jax top_k order)
            for (int off = 32; off; off >>= 1) {
                double ov = __shfl_xor(bv, off);
                int    on = __shfl_xor(bn, off);
                if (ov > bv || (ov == bv && on < bn)) { bv = ov; bn = on; }
            }
            if ((bn & 63) == lane) mask |= 1u << (bn >> 6);
            if (k == 0) t0 = bv;

            // softmax numerator: exp((sim_k - sim_max) * 0.125), 0.125 exact
            float ek = expf((float)((bv - t0) * 0.125));
            esum += ek;

            // spike = round(sigmoid(diag*v)) == (diag*v > 0) exactly
            float dg = diagD[bn * 64 + lane];
            float m  = dg * vlane;
            if (m > 0.f) outAcc += ek * o_vec[bn * 64 + lane];

            if (lane == 0) atomicMax(psiRow + bn, s);
        }
        OutMid[(size_t)tok * INNER_ + h * D_ + lane] = outAcc / esum;
    }
}

// ---------------------------------------------------------------------------
// K3: final = OutMid(8192x512) @ W_out(512x1024) + b_out -> fp32 d_out
// ---------------------------------------------------------------------------
#define BK3 16
__global__ __launch_bounds__(256) void k3_out(const float* __restrict__ A,
                                              const float* __restrict__ Wout,
                                              const float* __restrict__ bout,
                                              float* __restrict__ out) {
    __shared__ float as[64][BK3 + 1];
    __shared__ float bs[BK3][64 + 1];
    const int tx = threadIdx.x & 15, ty = threadIdx.x >> 4;
    const int mBase = blockIdx.y * 64, nBase = blockIdx.x * 64;

    float acc[4][4];
#pragma unroll
    for (int a = 0; a < 4; a++)
#pragma unroll
        for (int b = 0; b < 4; b++) acc[a][b] = 0.f;

    for (int k0 = 0; k0 < INNER_; k0 += BK3) {
        for (int i = threadIdx.x; i < 64 * BK3; i += 256) {
            int r = i >> 4, kk = i & 15;
            as[r][kk] = A[(size_t)(mBase + r) * INNER_ + k0 + kk];
        }
        for (int i = threadIdx.x; i < BK3 * 64; i += 256) {
            int kk = i >> 6, c = i & 63;
            bs[kk][c] = Wout[(size_t)(k0 + kk) * DIM_ + nBase + c];
        }
        __syncthreads();
#pragma unroll
        for (int kk = 0; kk < BK3; ++kk) {
            float xa[4], wb[4];
#pragma unroll
            for (int a = 0; a < 4; a++) xa[a] = as[ty * 4 + a][kk];
#pragma unroll
            for (int b = 0; b < 4; b++) wb[b] = bs[kk][tx * 4 + b];
#pragma unroll
            for (int a = 0; a < 4; a++)
#pragma unroll
                for (int b = 0; b < 4; b++)
                    acc[a][b] += xa[a] * wb[b];
        }
        __syncthreads();
    }

    const int mr = mBase + ty * 4, nc = nBase + tx * 4;
#pragma unroll
    for (int a = 0; a < 4; a++)
#pragma unroll
        for (int b = 0; b < 4; b++)
            out[(size_t)(mr + a) * DIM_ + nc + b] = acc[a][b] + bout[nc + b];
}

// ---------------------------------------------------------------------------
// K4: psi[n][d] = winner<0 ? 0 : (1-sigmoid(m))*m, m = diag[n][d]*v[s][d]
//     (fp32 output)
// ---------------------------------------------------------------------------
__global__ void k4_psi(const int*   __restrict__ psiRow,
                       const float* __restrict__ V,
                       const float* __restrict__ diagD,
                       float* __restrict__ psiOut) {
    int t = blockIdx.x * 256 + threadIdx.x;
    if (t >= NUMB_ * D_) return;
    int n = t >> 6, d = t & 63;
    int s = psiRow[n];
    float val = 0.f;
    if (s >= 0) {
        int b = s >> 14, h = (s >> 11) & 7, i = s & 2047;
        int tok = b * SEQ_ + i;
        float v  = V[(size_t)tok * INNER_ + h * D_ + d];
        float m  = diagD[t] * v;
        float sg = 1.f / (1.f + expf(-m));
        val = (1.f - sg) * m;
    }
    psiOut[t] = val;
}

// ---------------------------------------------------------------------------
extern "C" void kernel_launch(void* const* d_in, const int* in_sizes, int n_in,
                              void* d_out, int out_size, void* d_ws, size_t ws_size,
                              hipStream_t stream) {
    const float* x    = (const float*)d_in[0];
    const float* Wqv  = (const float*)d_in[1];
    const float* Wout = (const float*)d_in[2];
    const float* bout = (const float*)d_in[3];
    const float* bmat = (const float*)d_in[4];
    const float* kvec = (const float*)d_in[5];
    const float* ovec = (const float*)d_in[6];
    float* out = (float*)d_out;   // reference outputs are float32 (no bf16!)

    char* ws = (char*)d_ws;
    float*  diagD  = (float*) (ws);                       //   256,000 B
    float*  kT     = (float*) (ws + 256000);              //   256,000 B
    int*    psiRow = (int*)   (ws + 512000);              //     4,000 B
    float*  V      = (float*) (ws + (1u  << 20));         // 16 MiB  [1,17) MiB
    float*  OutMid = (float*) (ws + (17u << 20));         // 16 MiB  [17,33) MiB
    double* Qh     = (double*)(ws + (33u << 20));         // 16 MiB  [33,49) MiB
    // total 49 MiB of d_ws

    k0_prep<<<(NUMB_ * D_ + 255) / 256, 256, 0, stream>>>(bmat, kvec, diagD, kT, psiRow);

    for (int p = 0; p < 2; ++p) {
        k1_qv <<<dim3(16, PH_TOK_ / 64), 256, 0, stream>>>(x, Wqv, Qh, V, p * PH_TOK_);
        k2_sim<<<PH_ROWS_ / 16, 256, 0, stream>>>(Qh, V, kT, diagD, ovec, OutMid,
                                                  psiRow, p * PH_ROWS_, p * PH_TOK_);
    }

    k3_out<<<dim3(16, 128), 256, 0, stream>>>(OutMid, Wout, bout, out);
    k4_psi<<<(NUMB_ * D_ + 255) / 256, 256, 0, stream>>>(psiRow, V, diagD,
                                                         out + (size_t)TOK_ * DIM_);
}

// Round 5
// 1974.997 us; speedup vs baseline: 1.3381x; 1.3381x over previous
//
#include <hip/hip_runtime.h>
#include <math.h>

// Problem constants
#define H_     8
#define D_     64
#define TOPK_  32
#define NUMB_  1000
#define DIM_   1024
#define BATCH_ 4
#define SEQ_   2048
#define INNER_ 512                  // H*D
#define TOK_   (BATCH_*SEQ_)        // 8192
#define ROWS_  (BATCH_*H_*SEQ_)     // 65536

// Phase split: 2 phases, each covers 2 batches = 4096 tokens = 32768 sim rows.
#define PH_TOK_  4096
#define PH_ROWS_ 32768

// ---------------------------------------------------------------------------
// Workspace layout — TOTAL 49 MiB.
//   [0)          diagD   fp32 1000*64            = 256,000 B
//   [256000)     kT      fp32 64*1000            = 256,000 B
//   [512000)     psiRow  int  1000               =   4,000 B
//   [1 MiB)      V       fp32 8192*512           = 16 MiB   (all tokens)
//   [17 MiB)     OutMid  fp32 8192*512           = 16 MiB   (all tokens)
//   [33 MiB)     Qh      fp64 4096*512           = 16 MiB   (per-phase half)
// ---------------------------------------------------------------------------

// ---------------------------------------------------------------------------
// K0: diag(b_mat) -> diagD[n][d]; transpose k_vec -> kT[d][n]; psiRow = -1.
// ---------------------------------------------------------------------------
__global__ void k0_prep(const float* __restrict__ b_mat,
                        const float* __restrict__ k_vec,
                        float* __restrict__ diagD,
                        float* __restrict__ kT,
                        int*   __restrict__ psiRow) {
    int t = blockIdx.x * 256 + threadIdx.x;
    if (t < NUMB_ * D_) {
        int n = t >> 6, d = t & 63;
        diagD[t] = b_mat[n * (D_ * D_) + d * (D_ + 1)];   // b_mat[n][d][d]
        kT[d * NUMB_ + n] = k_vec[t];                     // k_vec[n][d]
    }
    if (t < NUMB_) psiRow[t] = -1;
}

// ---------------------------------------------------------------------------
// K1: qv = x @ W_qv for tokens [tokBase, tokBase+PH_TOK_), fp64 accumulation
//     of exact fp32 products (order-independent => stable top-k later).
// ---------------------------------------------------------------------------
#define BK1 16
__global__ __launch_bounds__(256) void k1_qv(const float* __restrict__ x,
                                             const float* __restrict__ Wqv,
                                             double* __restrict__ Qh,
                                             float*  __restrict__ V,
                                             int tokBase) {
    __shared__ float xs[64][BK1 + 1];
    __shared__ float ws[BK1][64 + 1];
    const int tx = threadIdx.x & 15, ty = threadIdx.x >> 4;
    const int mBase = tokBase + blockIdx.y * 64;   // global token row
    const int nBase = blockIdx.x * 64;

    double acc[4][4];
#pragma unroll
    for (int a = 0; a < 4; a++)
#pragma unroll
        for (int b = 0; b < 4; b++) acc[a][b] = 0.0;

    for (int k0 = 0; k0 < DIM_; k0 += BK1) {
        for (int i = threadIdx.x; i < 64 * BK1; i += 256) {
            int r = i >> 4, kk = i & 15;
            xs[r][kk] = x[(size_t)(mBase + r) * DIM_ + k0 + kk];
        }
        for (int i = threadIdx.x; i < BK1 * 64; i += 256) {
            int kk = i >> 6, c = i & 63;
            ws[kk][c] = Wqv[(size_t)(k0 + kk) * (2 * INNER_) + nBase + c];
        }
        __syncthreads();
#pragma unroll
        for (int kk = 0; kk < BK1; ++kk) {
            float xa[4], wb[4];
#pragma unroll
            for (int a = 0; a < 4; a++) xa[a] = xs[ty * 4 + a][kk];
#pragma unroll
            for (int b = 0; b < 4; b++) wb[b] = ws[kk][tx * 4 + b];
#pragma unroll
            for (int a = 0; a < 4; a++)
#pragma unroll
                for (int b = 0; b < 4; b++)
                    acc[a][b] += (double)xa[a] * (double)wb[b];
        }
        __syncthreads();
    }

    const int mr = mBase + ty * 4, nc = nBase + tx * 4;
    if (nc < INNER_) {
#pragma unroll
        for (int a = 0; a < 4; a++)
#pragma unroll
            for (int b = 0; b < 4; b++)
                Qh[(size_t)(mr - tokBase + a) * INNER_ + nc + b] = acc[a][b];
    } else {
#pragma unroll
        for (int a = 0; a < 4; a++)
#pragma unroll
            for (int b = 0; b < 4; b++)
                V[(size_t)(mr + a) * INNER_ + (nc - INNER_) + b] = (float)acc[a][b];
    }
}

// ---------------------------------------------------------------------------
// K2: one wave handles 4 sim rows. fp64 sim dot (exact products). Top-32 via
//     ballot-based bit-descent on a monotone 32-bit key (NO shuffle chains);
//     fp64-exact boundary resolution (rare path). Softmax offset-free
//     (|sim*0.125| <= ~0.2, exp well-conditioned). Selection set is
//     bit-identical to exact-fp64 top-k with (value desc, index asc) ties.
// ---------------------------------------------------------------------------
__global__ __launch_bounds__(256) void k2_sim(const double* __restrict__ Qh,
                                              const float*  __restrict__ V,
                                              const float*  __restrict__ kT,
                                              const float*  __restrict__ diagD,
                                              const float*  __restrict__ o_vec,
                                              float* __restrict__ OutMid,
                                              int*   __restrict__ psiRow,
                                              int sBase0, int tokOff) {
    __shared__ double qld[4][4][64];          // [wave][row][d]
    const int lane = threadIdx.x & 63;
    const int wid  = threadIdx.x >> 6;
    const int g    = blockIdx.x * 4 + wid;
    const int sBase = sBase0 + g * 4;

#pragma unroll
    for (int r = 0; r < 4; r++) {
        int s = sBase + r;
        int b = s >> 14, h = (s >> 11) & 7, i = s & 2047;
        int tok = b * SEQ_ + i;
        qld[wid][r][lane] = Qh[(size_t)(tok - tokOff) * INNER_ + h * D_ + lane];
    }
    __syncthreads();

    double acc[4][16];
#pragma unroll
    for (int r = 0; r < 4; r++)
#pragma unroll
        for (int nb = 0; nb < 16; nb++) acc[r][nb] = 0.0;

    for (int d = 0; d < 64; ++d) {
        double q0 = qld[wid][0][d];
        double q1 = qld[wid][1][d];
        double q2 = qld[wid][2][d];
        double q3 = qld[wid][3][d];
        const float* kp = kT + d * NUMB_;
#pragma unroll
        for (int nb = 0; nb < 16; ++nb) {
            int n = nb * 64 + lane;
            float kv = (n < NUMB_) ? kp[n] : 0.f;
            double kd = (double)kv;
            acc[0][nb] += q0 * kd;
            acc[1][nb] += q1 * kd;
            acc[2][nb] += q2 * kd;
            acc[3][nb] += q3 * kd;
        }
    }

#pragma unroll
    for (int r = 0; r < 4; r++) {
        int s = sBase + r;
        int b = s >> 14, h = (s >> 11) & 7, i = s & 2047;
        int tok = b * SEQ_ + i;
        float vlane = V[(size_t)tok * INNER_ + h * D_ + lane];

        // ---- monotone 32-bit keys (fp32 round of fp64 sim; non-strict) ----
        unsigned key[16];
#pragma unroll
        for (int nb = 0; nb < 16; ++nb) {
            int n = nb * 64 + lane;
            float f = (float)acc[r][nb];
            unsigned u = __float_as_uint(f);
            unsigned kk = (u & 0x80000000u) ? ~u : (u | 0x80000000u);
            key[nb] = (n < NUMB_) ? kk : 0u;   // invalid slots below all reals
        }

        // ---- bit-descent: tau = 32nd-largest key (count via ballot) ----
        unsigned tau = 0u;
        for (int bit = 31; bit >= 0; --bit) {
            unsigned cand = tau | (1u << bit);
            int c = 0;
#pragma unroll
            for (int nb = 0; nb < 16; ++nb)
                c += __popcll(__ballot(key[nb] >= cand));
            if (c >= TOPK_) tau = cand;
        }

        float esum = 0.f, outAcc = 0.f;
        int cgt = 0;

        // ---- definite members: key > tau (fp64-dominate all eq slots) ----
#pragma unroll
        for (int nb = 0; nb < 16; ++nb) {
            bool isgt = (key[nb] > tau);
            unsigned long long mm = __ballot(isgt);
            cgt += __popcll(mm);
            if (isgt) atomicMax(psiRow + nb * 64 + lane, s);
            while (mm) {
                int l = __ffsll((long long)mm) - 1; mm &= mm - 1;
                int n = nb * 64 + l;
                double v = __shfl(acc[r][nb], l);
                float ek = expf((float)v * 0.125f);
                esum += ek;
                float dg = diagD[n * 64 + lane];
                float mpot = dg * vlane;
                if (mpot > 0.f) outAcc += ek * o_vec[n * 64 + lane];
            }
        }

        int needed = TOPK_ - cgt;   // >= 1 always
        int ceq = 0;
#pragma unroll
        for (int nb = 0; nb < 16; ++nb)
            ceq += __popcll(__ballot(key[nb] == tau));

        if (ceq == needed) {
            // common case: all boundary slots are members
#pragma unroll
            for (int nb = 0; nb < 16; ++nb) {
                bool iseq = (key[nb] == tau);
                unsigned long long mm = __ballot(iseq);
                if (iseq) atomicMax(psiRow + nb * 64 + lane, s);
                while (mm) {
                    int l = __ffsll((long long)mm) - 1; mm &= mm - 1;
                    int n = nb * 64 + l;
                    double v = __shfl(acc[r][nb], l);
                    float ek = expf((float)v * 0.125f);
                    esum += ek;
                    float dg = diagD[n * 64 + lane];
                    float mpot = dg * vlane;
                    if (mpot > 0.f) outAcc += ek * o_vec[n * 64 + lane];
                }
            }
        } else {
            // rare: fp32-key collision straddles the boundary. Resolve the
            // `needed` largest among eq-candidates by exact fp64 value
            // (tie -> lowest index), via classic wave butterfly argmax.
            unsigned takenMask = 0u;
            for (int t = 0; t < needed; ++t) {
                double bv = -1e300; int bn = 0x7fffffff;
#pragma unroll
                for (int nb = 0; nb < 16; ++nb) {
                    int n = nb * 64 + lane;
                    bool candt = (key[nb] == tau) && !(takenMask & (1u << nb))
                                 && (n < NUMB_);
                    double v = acc[r][nb];
                    if (candt && (v > bv || (v == bv && n < bn))) { bv = v; bn = n; }
                }
                for (int off = 32; off; off >>= 1) {
                    double ov = __shfl_xor(bv, off);
                    int    on = __shfl_xor(bn, off);
                    if (ov > bv || (ov == bv && on < bn)) { bv = ov; bn = on; }
                }
                if ((bn & 63) == lane) takenMask |= 1u << (bn >> 6);
                float ek = expf((float)bv * 0.125f);
                esum += ek;
                float dg = diagD[bn * 64 + lane];
                float mpot = dg * vlane;
                if (mpot > 0.f) outAcc += ek * o_vec[bn * 64 + lane];
                if (lane == 0) atomicMax(psiRow + bn, s);
            }
        }

        OutMid[(size_t)tok * INNER_ + h * D_ + lane] = outAcc / esum;
    }
}

// ---------------------------------------------------------------------------
// K3: final = OutMid(8192x512) @ W_out(512x1024) + b_out -> fp32 d_out
// ---------------------------------------------------------------------------
#define BK3 16
__global__ __launch_bounds__(256) void k3_out(const float* __restrict__ A,
                                              const float* __restrict__ Wout,
                                              const float* __restrict__ bout,
                                              float* __restrict__ out) {
    __shared__ float as[64][BK3 + 1];
    __shared__ float bs[BK3][64 + 1];
    const int tx = threadIdx.x & 15, ty = threadIdx.x >> 4;
    const int mBase = blockIdx.y * 64, nBase = blockIdx.x * 64;

    float acc[4][4];
#pragma unroll
    for (int a = 0; a < 4; a++)
#pragma unroll
        for (int b = 0; b < 4; b++) acc[a][b] = 0.f;

    for (int k0 = 0; k0 < INNER_; k0 += BK3) {
        for (int i = threadIdx.x; i < 64 * BK3; i += 256) {
            int r = i >> 4, kk = i & 15;
            as[r][kk] = A[(size_t)(mBase + r) * INNER_ + k0 + kk];
        }
        for (int i = threadIdx.x; i < BK3 * 64; i += 256) {
            int kk = i >> 6, c = i & 63;
            bs[kk][c] = Wout[(size_t)(k0 + kk) * DIM_ + nBase + c];
        }
        __syncthreads();
#pragma unroll
        for (int kk = 0; kk < BK3; ++kk) {
            float xa[4], wb[4];
#pragma unroll
            for (int a = 0; a < 4; a++) xa[a] = as[ty * 4 + a][kk];
#pragma unroll
            for (int b = 0; b < 4; b++) wb[b] = bs[kk][tx * 4 + b];
#pragma unroll
            for (int a = 0; a < 4; a++)
#pragma unroll
                for (int b = 0; b < 4; b++)
                    acc[a][b] += xa[a] * wb[b];
        }
        __syncthreads();
    }

    const int mr = mBase + ty * 4, nc = nBase + tx * 4;
#pragma unroll
    for (int a = 0; a < 4; a++)
#pragma unroll
        for (int b = 0; b < 4; b++)
            out[(size_t)(mr + a) * DIM_ + nc + b] = acc[a][b] + bout[nc + b];
}

// ---------------------------------------------------------------------------
// K4: psi[n][d] = winner<0 ? 0 : (1-sigmoid(m))*m, m = diag[n][d]*v[s][d]
// ---------------------------------------------------------------------------
__global__ void k4_psi(const int*   __restrict__ psiRow,
                       const float* __restrict__ V,
                       const float* __restrict__ diagD,
                       float* __restrict__ psiOut) {
    int t = blockIdx.x * 256 + threadIdx.x;
    if (t >= NUMB_ * D_) return;
    int n = t >> 6, d = t & 63;
    int s = psiRow[n];
    float val = 0.f;
    if (s >= 0) {
        int b = s >> 14, h = (s >> 11) & 7, i = s & 2047;
        int tok = b * SEQ_ + i;
        float v  = V[(size_t)tok * INNER_ + h * D_ + d];
        float m  = diagD[t] * v;
        float sg = 1.f / (1.f + expf(-m));
        val = (1.f - sg) * m;
    }
    psiOut[t] = val;
}

// ---------------------------------------------------------------------------
extern "C" void kernel_launch(void* const* d_in, const int* in_sizes, int n_in,
                              void* d_out, int out_size, void* d_ws, size_t ws_size,
                              hipStream_t stream) {
    const float* x    = (const float*)d_in[0];
    const float* Wqv  = (const float*)d_in[1];
    const float* Wout = (const float*)d_in[2];
    const float* bout = (const float*)d_in[3];
    const float* bmat = (const float*)d_in[4];
    const float* kvec = (const float*)d_in[5];
    const float* ovec = (const float*)d_in[6];
    float* out = (float*)d_out;   // reference outputs are float32

    char* ws = (char*)d_ws;
    float*  diagD  = (float*) (ws);                       //   256,000 B
    float*  kT     = (float*) (ws + 256000);              //   256,000 B
    int*    psiRow = (int*)   (ws + 512000);              //     4,000 B
    float*  V      = (float*) (ws + (1u  << 20));         // 16 MiB  [1,17) MiB
    float*  OutMid = (float*) (ws + (17u << 20));         // 16 MiB  [17,33) MiB
    double* Qh     = (double*)(ws + (33u << 20));         // 16 MiB  [33,49) MiB

    k0_prep<<<(NUMB_ * D_ + 255) / 256, 256, 0, stream>>>(bmat, kvec, diagD, kT, psiRow);

    for (int p = 0; p < 2; ++p) {
        k1_qv <<<dim3(16, PH_TOK_ / 64), 256, 0, stream>>>(x, Wqv, Qh, V, p * PH_TOK_);
        k2_sim<<<PH_ROWS_ / 16, 256, 0, stream>>>(Qh, V, kT, diagD, ovec, OutMid,
                                                  psiRow, p * PH_ROWS_, p * PH_TOK_);
    }

    k3_out<<<dim3(16, 128), 256, 0, stream>>>(OutMid, Wout, bout, out);
    k4_psi<<<(NUMB_ * D_ + 255) / 256, 256, 0, stream>>>(psiRow, V, diagD,
                                                         out + (size_t)TOK_ * DIM_);
}